// Round 1
// baseline (270.023 us; speedup 1.0000x reference)
//
#include <hip/hip_runtime.h>
#include <cstdint>

// ---------------------------------------------------------------------------
// Threefry-2x32, 20 rounds — bit-exact match for JAX's threefry2x32_p.
// Key schedule: ks2 = 0x1BD11BDA ^ k0 ^ k1; rotation groups
// [13,15,26,6] / [17,29,16,24] alternating, key injection after each group.
// ---------------------------------------------------------------------------
static __device__ __forceinline__ uint32_t rotl32(uint32_t x, int r) {
  return (x << r) | (x >> (32 - r));
}

static __device__ __forceinline__ void threefry2x32(uint32_t k0, uint32_t k1,
                                                    uint32_t& x0, uint32_t& x1) {
  const uint32_t ks2 = 0x1BD11BDAu ^ k0 ^ k1;
  x0 += k0;
  x1 += k1;
#define TF_R(r)                        \
  x0 += x1;                            \
  x1 = rotl32(x1, (r));                \
  x1 ^= x0;
  TF_R(13) TF_R(15) TF_R(26) TF_R(6)
  x0 += k1;  x1 += ks2 + 1u;
  TF_R(17) TF_R(29) TF_R(16) TF_R(24)
  x0 += ks2; x1 += k0 + 2u;
  TF_R(13) TF_R(15) TF_R(26) TF_R(6)
  x0 += k0;  x1 += k1 + 3u;
  TF_R(17) TF_R(29) TF_R(16) TF_R(24)
  x0 += k1;  x1 += ks2 + 4u;
  TF_R(13) TF_R(15) TF_R(26) TF_R(6)
  x0 += ks2; x1 += k0 + 5u;
#undef TF_R
}

// Per-row dropout scale, reproducing (partitionable threefry path):
//   bits[i] = o0 ^ o1, (o0,o1) = threefry((0,42), hi32(i)=0, lo32(i)=i)
//   u = bitcast((bits>>9)|0x3f800000) - 1.0f ;  keep = u < 0.9f
//   scale = keep ? 1/0.9 : 0
static __device__ __forceinline__ float row_scale(uint32_t v) {
  uint32_t a = 0u, b = v;
  threefry2x32(0u, 42u, a, b);
  const uint32_t bits = a ^ b;
  const float u = __uint_as_float((bits >> 9) | 0x3f800000u) - 1.0f;
  return (u < 0.9f) ? (1.0f / 0.9f) : 0.0f;
}

// One block per token; 256 threads x float4 = 1024 floats = one embedding row.
__global__ __launch_bounds__(256) void embed_dropout_kernel(
    const int* __restrict__ x, const float4* __restrict__ w4,
    float4* __restrict__ out4) {
  const int t = blockIdx.x;
  const uint32_t v = (uint32_t)x[t];
  const float scale = row_scale(v);

  const int tid = threadIdx.x;
  float4 wv = w4[(size_t)v * 256u + (size_t)tid];
  wv.x *= scale;
  wv.y *= scale;
  wv.z *= scale;
  wv.w *= scale;
  out4[(size_t)t * 256u + (size_t)tid] = wv;
}

extern "C" void kernel_launch(void* const* d_in, const int* in_sizes, int n_in,
                              void* d_out, int out_size, void* d_ws, size_t ws_size,
                              hipStream_t stream) {
  const int* x = (const int*)d_in[0];          // [8,2048] token ids (int32)
  const float* w = (const float*)d_in[1];      // [50257,1024] f32
  float* out = (float*)d_out;                  // [8,2048,1024] f32

  const int tokens = in_sizes[0];              // 16384
  embed_dropout_kernel<<<tokens, 256, 0, stream>>>(
      x, (const float4*)w, (float4*)out);
}